// Round 3
// baseline (249.141 us; speedup 1.0000x reference)
//
#include <hip/hip_runtime.h>

#define HOP 256
#define SEG 1024
#define BLOCK 256
#define UNROLL 8

typedef float f32x4 __attribute__((ext_vector_type(4)));

// y[b,i] = x[b,i] * W[pos],  W[pos] = sum_{m=0..3} aw[r+256m]*sw[r+256m]
//   r = pos & 255, blk = pos >> 8, term m included iff blk >= m && blk-m <= kmax.
//
// Launch config guarantees stride*4 == 2N (multiple of N), so pos/blk/W are
// invariant across all UNROLL accesses of a thread -> compute W once.
// All UNROLL loads are issued before any store (8 global_load_dwordx4 in
// flight per wave = 8 KB), then plain stores. NT store reverted: round-1 A/B
// showed `nt` did not reduce FETCH_SIZE (no L3-retention effect) and cost
// ~25% duration (2.49 -> 1.9 TB/s) -- write path through L2 is faster.
//
// (Round-2 submission was lost to an infra failure; this is the same kernel
// resubmitted unchanged to preserve the A/B vs round 1.)
__global__ __launch_bounds__(BLOCK) void SegmenterTensorFlow_28698971472345_kernel(
    const f32x4* __restrict__ x4,
    const float* __restrict__ aw,
    const float* __restrict__ sw,
    f32x4* __restrict__ y4,
    int n_mask,          // N - 1 (N power of two)
    int kmax)            // num_segments - 1 = 8188
{
    const int tid    = blockIdx.x * BLOCK + threadIdx.x;
    const int stride = gridDim.x * BLOCK;   // float4 stride; stride*4 % N == 0

    const int pos = (tid * 4) & n_mask;     // invariant across the unroll
    const int r   = pos & (HOP - 1);
    const int blk = pos >> 8;               // wave-uniform (64 lanes * 4 = HOP)

    float wx = 0.f, wy = 0.f, wz = 0.f, ww = 0.f;
#pragma unroll
    for (int m = 0; m < 4; ++m) {
        if (blk >= m && (blk - m) <= kmax) {
            const float* pa = aw + r + m * HOP;
            const float* ps = sw + r + m * HOP;
            wx += pa[0] * ps[0];
            wy += pa[1] * ps[1];
            wz += pa[2] * ps[2];
            ww += pa[3] * ps[3];
        }
    }
    const f32x4 w = {wx, wy, wz, ww};

    // Batch all loads: 8 outstanding vmem ops per wave before any store.
    f32x4 xv[UNROLL];
#pragma unroll
    for (int u = 0; u < UNROLL; ++u)
        xv[u] = x4[tid + u * stride];

#pragma unroll
    for (int u = 0; u < UNROLL; ++u)
        y4[tid + u * stride] = xv[u] * w;
}

extern "C" void kernel_launch(void* const* d_in, const int* in_sizes, int n_in,
                              void* d_out, int out_size, void* d_ws, size_t ws_size,
                              hipStream_t stream) {
    const float* x  = (const float*)d_in[0];
    const float* aw = (const float*)d_in[1];
    const float* sw = (const float*)d_in[2];

    const int N = 1 << 21;                  // samples per row (power of two)
    const int total4 = out_size / 4;        // 8,388,608 float4s
    const int kmax = (N - SEG) / HOP;       // 8188

    dim3 block(BLOCK);
    dim3 grid(total4 / (BLOCK * UNROLL));   // 4096 -> stride*4 = 2N exactly

    SegmenterTensorFlow_28698971472345_kernel<<<grid, block, 0, stream>>>(
        (const f32x4*)x, aw, sw, (f32x4*)d_out, N - 1, kmax);
}

// Round 4
// 224.906 us; speedup vs baseline: 1.1078x; 1.1078x over previous
//
#include <hip/hip_runtime.h>

#define HOP 256
#define SEG 1024
#define BLOCK 256

typedef float f32x4 __attribute__((ext_vector_type(4)));

// y[b,i] = x[b,i] * W[pos],  W[pos] = sum_{m=0..3} aw[r+256m]*sw[r+256m]
//   r = pos & 255, blk = pos >> 8, term m included iff blk >= m && blk-m <= kmax.
//
// Key facts driving this structure (rounds 0-3 A/B evidence):
//  - TLP already covers latency hiding (21 waves/CU x 1KB >> 9KB needed);
//    per-wave batched loads HURT (81 -> 97 us). So: copy-ubench shape --
//    one float4 per thread, one-shot blocks, no loop-carried vmcnt chains.
//  - NT stores hurt (no L3-retention benefit, +10 us). Plain stores.
//  - For interior blocks (3 <= blk <= kmax) all 4 terms are included, so
//    W depends only on r = pos & 255: a 256-entry table. Build it in LDS
//    once per block (L1-hot window loads), overlapped with the x load.
__global__ __launch_bounds__(BLOCK) void SegmenterTensorFlow_28698971472345_kernel(
    const f32x4* __restrict__ x4,
    const float* __restrict__ aw,
    const float* __restrict__ sw,
    f32x4* __restrict__ y4,
    int n_mask,          // N - 1 (N power of two)
    int kmax)            // num_segments - 1 = 8188
{
    const int tid = blockIdx.x * BLOCK + threadIdx.x;

    // Issue the bulk load first; everything below overlaps its latency.
    const f32x4 xv = x4[tid];

    // Build the combined-window table for this block: wt[r] = sum_m aw*sw.
    __shared__ float wt[HOP];
    {
        const int i = threadIdx.x;          // 256 threads <-> 256 entries
        float acc = 0.f;
#pragma unroll
        for (int m = 0; m < 4; ++m)
            acc += aw[i + m * HOP] * sw[i + m * HOP];
        wt[i] = acc;
    }
    __syncthreads();

    const int pos = (tid * 4) & n_mask;     // position within the row
    const int blk = pos >> 8;               // wave-uniform (64 lanes * 4 = HOP)
    const int r   = pos & (HOP - 1);

    f32x4 w;
    if (blk >= 3 && blk <= kmax) {
        // interior: all 4 terms -> straight table lookup (ds_read_b128)
        w = reinterpret_cast<const f32x4*>(wt)[r >> 2];
    } else {
        // edge blocks (6 of 8192 per row), wave-uniform branch: direct sum
        float e[4] = {0.f, 0.f, 0.f, 0.f};
#pragma unroll
        for (int m = 0; m < 4; ++m) {
            if (blk >= m && (blk - m) <= kmax) {
#pragma unroll
                for (int j = 0; j < 4; ++j)
                    e[j] += aw[r + j + m * HOP] * sw[r + j + m * HOP];
            }
        }
        w = f32x4{e[0], e[1], e[2], e[3]};
    }

    y4[tid] = xv * w;
}

extern "C" void kernel_launch(void* const* d_in, const int* in_sizes, int n_in,
                              void* d_out, int out_size, void* d_ws, size_t ws_size,
                              hipStream_t stream) {
    const float* x  = (const float*)d_in[0];
    const float* aw = (const float*)d_in[1];
    const float* sw = (const float*)d_in[2];

    const int N = 1 << 21;                  // samples per row (power of two)
    const int total4 = out_size / 4;        // 8,388,608 float4s
    const int kmax = (N - SEG) / HOP;       // 8188

    dim3 block(BLOCK);
    dim3 grid(total4 / BLOCK);              // 32768 one-shot blocks

    SegmenterTensorFlow_28698971472345_kernel<<<grid, block, 0, stream>>>(
        (const f32x4*)x, aw, sw, (f32x4*)d_out, N - 1, kmax);
}

// Round 5
// 221.874 us; speedup vs baseline: 1.1229x; 1.0137x over previous
//
#include <hip/hip_runtime.h>

#define HOP 256
#define SEG 1024
#define BLOCK 256

typedef float f32x4 __attribute__((ext_vector_type(4)));

// y[b,i] = x[b,i] * W[pos],  W[pos] = sum_{m=0..3} aw[r+256m]*sw[r+256m]
//   r = pos & 255, blk = pos >> 8, term m included iff blk >= m && blk-m <= kmax.
//
// Evidence so far (rounds 0-4):
//  - One-shot copy-shaped structure + LDS weight table: best (per-dispatch ~75us).
//  - Per-wave batched loads HURT; NT *stores* hurt (+10us, no traffic change).
//  - Harness's own fillBuffer runs 6.7 TB/s pure-write => machine can stream.
//  - FETCH = exactly half of x every dispatch: y's write-allocations evict
//    half of x from L3, leaving the HBM read stream as a random 128B-granular
//    hit/miss interleave -> DRAM row locality destroyed (~1.1 TB/s effective
//    read rate by subtraction).
// This round's single change: NT *loads* on x. If nt makes reads no-allocate
// in L2/MALL, x stops competing with y for L3 and the HBM read stream becomes
// fully contiguous. Signature: FETCH_SIZE 65.6 -> ~131 MB.
__global__ __launch_bounds__(BLOCK) void SegmenterTensorFlow_28698971472345_kernel(
    const f32x4* __restrict__ x4,
    const float* __restrict__ aw,
    const float* __restrict__ sw,
    f32x4* __restrict__ y4,
    int n_mask,          // N - 1 (N power of two)
    int kmax)            // num_segments - 1 = 8188
{
    const int tid = blockIdx.x * BLOCK + threadIdx.x;

    // Bulk load first (non-temporal: stream past L3), overlap everything below.
    const f32x4 xv = __builtin_nontemporal_load(&x4[tid]);

    // Combined-window table for this block: wt[r] = sum_m aw[r+256m]*sw[r+256m].
    __shared__ float wt[HOP];
    {
        const int i = threadIdx.x;          // 256 threads <-> 256 entries
        float acc = 0.f;
#pragma unroll
        for (int m = 0; m < 4; ++m)
            acc += aw[i + m * HOP] * sw[i + m * HOP];
        wt[i] = acc;
    }
    __syncthreads();

    const int pos = (tid * 4) & n_mask;     // position within the row
    const int blk = pos >> 8;               // wave-uniform (64 lanes * 4 = HOP)
    const int r   = pos & (HOP - 1);

    f32x4 w;
    if (blk >= 3 && blk <= kmax) {
        // interior: all 4 terms -> straight table lookup (ds_read_b128)
        w = reinterpret_cast<const f32x4*>(wt)[r >> 2];
    } else {
        // edge blocks (6 of 8192 per row), wave-uniform branch: direct sum
        float e[4] = {0.f, 0.f, 0.f, 0.f};
#pragma unroll
        for (int m = 0; m < 4; ++m) {
            if (blk >= m && (blk - m) <= kmax) {
#pragma unroll
                for (int j = 0; j < 4; ++j)
                    e[j] += aw[r + j + m * HOP] * sw[r + j + m * HOP];
            }
        }
        w = f32x4{e[0], e[1], e[2], e[3]};
    }

    y4[tid] = xv * w;   // plain store (NT-store was a measured regression)
}

extern "C" void kernel_launch(void* const* d_in, const int* in_sizes, int n_in,
                              void* d_out, int out_size, void* d_ws, size_t ws_size,
                              hipStream_t stream) {
    const float* x  = (const float*)d_in[0];
    const float* aw = (const float*)d_in[1];
    const float* sw = (const float*)d_in[2];

    const int N = 1 << 21;                  // samples per row (power of two)
    const int total4 = out_size / 4;        // 8,388,608 float4s
    const int kmax = (N - SEG) / HOP;       // 8188

    dim3 block(BLOCK);
    dim3 grid(total4 / BLOCK);              // 32768 one-shot blocks

    SegmenterTensorFlow_28698971472345_kernel<<<grid, block, 0, stream>>>(
        (const f32x4*)x, aw, sw, (f32x4*)d_out, N - 1, kmax);
}